// Round 5
// baseline (171.970 us; speedup 1.0000x reference)
//
#include <hip/hip_runtime.h>
#include <stdint.h>

// Simple exponential smoothing: level_t = (1-a)*level_{t-1} + a*y_t,
// level_0 = y_0 pinned via global initial carry s_{-1} = y_0.
// out[t] = level_t for t in [0, n-2].
//
// R13: hybrid REGISTER-TILE + LDS STORE-STAGING.
//   R12 post-mortem: adaptive halo neutral -> halo was already L2-absorbed
//   (same-XCD swizzle works). Residual gap = LDS round-trip (5 touches/elem,
//   3 barriers) + only 4 blocks/CU at 32KB LDS.
//   R13: SEG=16 -> per-thread tile = one 64B line (line-coalesced reads,
//   16 VGPRs - no spill regime), reduce+replay from registers; LDS (16KB)
//   only stages the OUTPUT for cooperative full-line NT stores. 2 barriers.
//   launch_bounds(256,8) -> 8 blocks/CU. Halo: gate (1-a)^1024 < 1e-8
//   (alpha > 0.018, P~98%; slow path exact fallback), halo = 1024 elems =
//   one float4/thread. Truncation <= 1e-8*|level|, ~3 orders under the
//   fp32-drift absmax (bit-identical 2^-10 across all rounds/structures).
//   Ledger (fills ~85us fixed): R8 41.5 | R9 57 (reg-spill @SEG=64) |
//   R10 118 (scattered stores: L2 RMW) | R11 28.7 | R12 30 (neutral).
//   emit floor = 128MB stream ~ 20us.
// Bans (measured): in-kernel grid sync (R2 ~80us, R7 ~125us — cross-XCD),
// coop launch (R4: graph-capture reject), per-thread direct float4 stores
// of contiguous segments (R10: L2 RMW), bulk register tile >= 64 floats
// (R9: scratch spill).
//
// Affine pairs (a,b): s_out = a*s_in + b.
// combine(earlier=(a1,b1), later=(a2,b2)) = (a1*a2, a2*b1 + b2).

#define BLOCK 256
#define SEG   16                  // elements per thread = one 64B line
#define VPT   (SEG / 4)           // 4 float4 per thread
#define CHUNK (BLOCK * SEG)       // 4096 elements per block
#define NF4   (CHUNK / 4)         // 1024 float4 slots in LDS
#define HALO  1024                // windowed-carry history length
#define DECAY_THR 1e-8f           // fast path iff (1-a)^HALO < this

typedef float f32x4 __attribute__((ext_vector_type(4)));

__device__ __forceinline__ void nt_store4(float* p, float x, float y, float z, float w) {
    f32x4 v = {x, y, z, w};
    __builtin_nontemporal_store(v, (f32x4*)p);
}

// Bank-group swizzle on float4 index (involution): both access modes
// (replay-write j=t*4+v and store-read j=t+256k) hit all 8 groups uniformly.
__device__ __forceinline__ int sw(int j) { return j ^ ((j >> 3) & 7); }

// x^(2^k) via repeated squaring
__device__ __forceinline__ float pow2k(float x, int k) {
    float p = x;
#pragma unroll
    for (int i = 0; i < k; ++i) p *= p;
    return p;
}

// Inclusive affine scan across the 64 lanes of a wave (shuffle-based).
__device__ __forceinline__ void wave_scan_affine(float& a, float& b) {
    const int lane = threadIdx.x & 63;
#pragma unroll
    for (int off = 1; off < 64; off <<= 1) {
        float pa = __shfl_up(a, off);
        float pb = __shfl_up(b, off);
        if (lane >= off) {
            b = fmaf(a, pb, b);   // later.a * earlier.b + later.b
            a = pa * a;
        }
    }
}

// Block-wide EXCLUSIVE affine scan (identity for t=0). wa/wb: 4-float LDS
// scratch; caller barriers before reuse. Internal barrier between write/read.
__device__ __forceinline__ void block_exscan_affine(
    float a, float b, float* wa, float* wb, int t, float& ea, float& eb)
{
    float ia = a, ib = b;
    wave_scan_affine(ia, ib);                 // inclusive within wave
    const int w = t >> 6, lane = t & 63;
    if (lane == 63) { wa[w] = ia; wb[w] = ib; }
    float xa = __shfl_up(ia, 1);
    float xb = __shfl_up(ib, 1);
    if (lane == 0) { xa = 1.0f; xb = 0.0f; }
    __syncthreads();
    float pa = 1.0f, pb = 0.0f;               // compose waves 0..w-1 in order
#pragma unroll
    for (int i = 0; i < 3; ++i) {
        if (i < w) {
            float ca = wa[i], cb = wb[i];
            pb = fmaf(ca, pb, cb);
            pa *= ca;
        }
    }
    eb = fmaf(xa, pb, xb);                    // combine(wavePrefix, laneExclusive)
    ea = pa * xa;
}

// Pass 1: per-block affine aggregate. Early-exits when the windowed-carry
// fast path applies (aggregates would never be read).
__global__ __launch_bounds__(BLOCK) void k_block_agg(
    const float* __restrict__ y, const float* __restrict__ alpha_p,
    float* __restrict__ aggA, float* __restrict__ aggB, long n)
{
    const float alpha = alpha_p[0];
    const float oma = 1.0f - alpha;
    if (pow2k(oma, 10) < DECAY_THR) return;   // fast path: skip pass 1 entirely

    const int t = threadIdx.x;
    const long base = (long)blockIdx.x * CHUNK + (long)t * SEG;

    float a = 1.0f, s = 0.0f;
    if (base + SEG <= n) {
        const float4* p = (const float4*)(y + base);
#pragma unroll
        for (int v = 0; v < VPT; ++v) {
            float4 q = p[v];
            s = fmaf(oma, s, alpha * q.x);
            s = fmaf(oma, s, alpha * q.y);
            s = fmaf(oma, s, alpha * q.z);
            s = fmaf(oma, s, alpha * q.w);
        }
        a = pow2k(oma, 4);                    // oma^SEG
    } else {
        for (int k = 0; k < SEG; ++k) {
            long idx = base + k;
            if (idx < n) { s = fmaf(oma, s, alpha * y[idx]); a *= oma; }
        }
    }

    __shared__ float wa[4], wb[4];
    wave_scan_affine(a, s);
    if ((t & 63) == 63) { wa[t >> 6] = a; wb[t >> 6] = s; }
    __syncthreads();
    if (t == 0) {
        float ta = 1.0f, tb = 0.0f;
#pragma unroll
        for (int i = 0; i < 4; ++i) {
            float ca = wa[i], cb = wb[i];
            tb = fmaf(ca, tb, cb);
            ta *= ca;
        }
        aggA[blockIdx.x] = ta;
        aggB[blockIdx.x] = tb;
    }
}

// Pass 2: carry from 1024-elem halo (fast) or aggregate scan (slow);
// register tile; LDS stages output only; cooperative NT stores.
__global__ __launch_bounds__(BLOCK, 8) void k_emit(
    const float* __restrict__ y, const float* __restrict__ alpha_p,
    const float* __restrict__ aggA, const float* __restrict__ aggB,
    float* __restrict__ out, long n, int G)
{
    __shared__ float4 buf[NF4];          // 16 KB output stage
    __shared__ float wa[4], wb[4];       // exscan wave totals
    __shared__ float hwa[4], hwb[4];     // halo wave totals
    __shared__ float s_carry;

    const int t = threadIdx.x;
    // XCD-aware swizzle: consecutive tiles on one XCD. Bijective iff G%8==0.
    int tile = blockIdx.x;
    if ((G & 7) == 0) tile = (tile & 7) * (G >> 3) + (tile >> 3);

    const float alpha = alpha_p[0];
    const float oma   = 1.0f - alpha;
    const bool  fast  = (pow2k(oma, 10) < DECAY_THR);
    const long tbase = (long)tile * CHUNK;
    const long base  = tbase + (long)t * SEG;
    const bool fullTile = (tbase + CHUNK <= n);
    const float y0 = y[0];

    // ---- issue halo load first (independent, long-latency) ----
    const bool do_halo = fast && (tile > 0);  // tile>0 => tbase >= CHUNK >= HALO
    float4 hq;
    if (do_halo) {
        hq = ((const float4*)(y + (tbase - HALO)))[t];  // elems [.. +4t, +4)
    }

    // ---- tile load: one 64B line per thread, into registers ----
    float4 arr[VPT];
    if (fullTile) {
        const float4* p = (const float4*)(y + base);
#pragma unroll
        for (int v = 0; v < VPT; ++v) arr[v] = p[v];
    }

    // ---- halo reduce + wave scan; totals -> hwa/hwb (read after barrier) ----
    if (do_halo) {
        float hs = 0.0f;
        hs = fmaf(oma, hs, alpha * hq.x);
        hs = fmaf(oma, hs, alpha * hq.y);
        hs = fmaf(oma, hs, alpha * hq.z);
        hs = fmaf(oma, hs, alpha * hq.w);
        float ha = pow2k(oma, 2);              // oma^4
        wave_scan_affine(ha, hs);
        if ((t & 63) == 63) { hwa[t >> 6] = ha; hwb[t >> 6] = hs; }
    }

    // ---- per-thread segment reduce from registers ----
    float a_seg, b_seg;
    if (fullTile) {
        float s = 0.0f;
#pragma unroll
        for (int v = 0; v < VPT; ++v) {
            s = fmaf(oma, s, alpha * arr[v].x);
            s = fmaf(oma, s, alpha * arr[v].y);
            s = fmaf(oma, s, alpha * arr[v].z);
            s = fmaf(oma, s, alpha * arr[v].w);
        }
        b_seg = s;
        a_seg = pow2k(oma, 4);                 // oma^SEG
    } else {
        float a = 1.0f, s = 0.0f;
        for (int k = 0; k < SEG; ++k) {
            long idx = base + k;
            if (idx < n) { s = fmaf(oma, s, alpha * y[idx]); a *= oma; }
        }
        a_seg = a; b_seg = s;
    }

    // ---- tile exclusive scan (internal barrier makes hwa/hwb visible too) ----
    float ea_th, eb_th;
    block_exscan_affine(a_seg, b_seg, wa, wb, t, ea_th, eb_th);

    // ---- carry ----
    float carry = y0;                          // exact for tile 0
    if (do_halo) {
        float cb_ = 0.0f;                      // fold 4 wave totals in order;
#pragma unroll                                 // initial-state term <1e-8 dropped
        for (int i = 0; i < 4; ++i) cb_ = fmaf(hwa[i], cb_, hwb[i]);
        carry = cb_;
    }

    if (!fast) {
        // ---- slow path: redundant scan of G aggregates -> this tile's carry ----
        const int items = (G + BLOCK - 1) / BLOCK;   // 16 for G=4096
        float ta = 1.0f, tb = 0.0f;
        for (int j = 0; j < items; ++j) {
            int g = t * items + j;
            if (g < G) {
                float ca = aggA[g], cb = aggB[g];
                tb = fmaf(ca, tb, cb);
                ta *= ca;
            }
        }
        __syncthreads();                       // wa/wb reads (tile scan) done
        float pa, pb;
        block_exscan_affine(ta, tb, wa, wb, t, pa, pb);
        const int q = tile / items;            // owning thread for this tile's prefix
        if (t == q) {
            float ea = pa, eb = pb;            // aggregates [0, q*items)
            const int r = tile - q * items;    // remaining [q*items, tile)
            for (int j = 0; j < r; ++j) {
                int g = q * items + j;
                float ca = aggA[g], cb = aggB[g];
                eb = fmaf(ca, eb, cb);
                ea *= ca;
            }
            s_carry = fmaf(ea, y0, eb);        // level just before this tile
        }
        __syncthreads();
        carry = s_carry;
    }

    float lvl = fmaf(ea_th, carry, eb_th);     // level just before this segment

    // ---- replay from registers -> swizzled LDS; cooperative NT store ----
    if (fullTile) {
#pragma unroll
        for (int v = 0; v < VPT; ++v) {
            float4 q = arr[v], r;
            lvl = fmaf(oma, lvl, alpha * q.x); r.x = lvl;
            lvl = fmaf(oma, lvl, alpha * q.y); r.y = lvl;
            lvl = fmaf(oma, lvl, alpha * q.z); r.z = lvl;
            lvl = fmaf(oma, lvl, alpha * q.w); r.w = lvl;
            buf[sw(t * VPT + v)] = r;
        }
        __syncthreads();   // all replay writes visible
        const bool lastGuard = (tbase + CHUNK > n - 1);
#pragma unroll
        for (int k = 0; k < 4; ++k) {
            const int j = t + (k << 8);
            float4 r = buf[sw(j)];
            const long gi = tbase + 4L * j;
            if (!lastGuard) {
                nt_store4(out + gi, r.x, r.y, r.z, r.w);
            } else {
                if (gi + 4 <= n - 1) {
                    nt_store4(out + gi, r.x, r.y, r.z, r.w);
                } else {
                    if (gi + 0 < n - 1) out[gi + 0] = r.x;
                    if (gi + 1 < n - 1) out[gi + 1] = r.y;
                    if (gi + 2 < n - 1) out[gi + 2] = r.z;
                    if (gi + 3 < n - 1) out[gi + 3] = r.w;
                }
            }
        }
    } else {
        for (int k = 0; k < SEG; ++k) {
            long idx = base + k;
            if (idx < n) {
                lvl = fmaf(oma, lvl, alpha * y[idx]);
                if (idx < n - 1) out[idx] = lvl;
            }
        }
    }
}

extern "C" void kernel_launch(void* const* d_in, const int* in_sizes, int n_in,
                              void* d_out, int out_size, void* d_ws, size_t ws_size,
                              hipStream_t stream) {
    const float* y     = (const float*)d_in[0];
    const float* alpha = (const float*)d_in[1];
    float* out = (float*)d_out;
    const long n = (long)in_sizes[0];
    const int  G = (int)((n + CHUNK - 1) / CHUNK);   // 4096 for n = 2^24

    float* aggA = (float*)d_ws;        // G floats (written only on slow path)
    float* aggB = aggA + G;            // G floats

    k_block_agg<<<G, BLOCK, 0, stream>>>(y, alpha, aggA, aggB, n);
    k_emit<<<G, BLOCK, 0, stream>>>(y, alpha, aggA, aggB, out, n, G);
}

// Round 6
// 113.280 us; speedup vs baseline: 1.5181x; 1.5181x over previous
//
#include <hip/hip_runtime.h>
#include <stdint.h>

// Simple exponential smoothing: level_t = (1-a)*level_{t-1} + a*y_t,
// level_0 = y_0 pinned via global initial carry s_{-1} = y_0.
// out[t] = level_t for t in [0, n-2].
//
// R14 = R11 RESTORED VERBATIM (measured best: 113.7us total, emit ~25us).
//   R13 post-mortem: "register tile" with uses on both sides of a
//   barrier-bearing region was demoted by the compiler to global re-loads
//   (VGPR_Count=24 proves it) -> latency-bound replay, emit 76us. Only LDS
//   marshalling keeps replay operands reliably on-chip.
//   R12 post-mortem: adaptive halo neutral -> the 4096-elem halo is already
//   L2-absorbed via the same-XCD swizzle; not an HBM cost.
//   Roofline: emit streams 128MB mixed r+w; mixed-stream floor ~22-23us ->
//   R11's 25us is within ~10%. Total floor ~= 85 (harness fills, fixed) +
//   ~2.5 (agg early-exit dispatch) + ~23 + gaps ~= 112us vs 113.7 measured.
//   Structure: tile staged in LDS ONCE (32KB). Cooperative lane-contiguous
//   global loads -> LDS (XOR-swizzled float4 index j^((j>>3)&7): both
//   lane-contiguous and thread-segment modes conflict-free b128). Segment
//   reduce and replay read/write LDS in place; cooperative lane-contiguous
//   NT store emits full 64B lines. Fast path iff (1-a)^4096 < 1e-8: carry
//   from 4096-elem halo; truncation <= 1e-8*|level| (absmax bit-identical
//   2^-10 across slow/fast rounds). Exact 2-pass aggregate path for tiny
//   alpha (k_block_agg early-exits on fast path).
// Bans (measured): in-kernel grid sync (R2 ~80us, R7 ~125us — cross-XCD),
// coop launch (R4: graph-capture reject), per-thread direct float4 stores
// of contiguous segments (R10: L2 RMW), register tile consumed across
// barrier-bearing regions (R9 spill / R13 demotion to re-loads).
//
// Affine pairs (a,b): s_out = a*s_in + b.
// combine(earlier=(a1,b1), later=(a2,b2)) = (a1*a2, a2*b1 + b2).

#define BLOCK 256
#define SEG   32                  // elements per thread
#define VPT   (SEG / 4)           // 8 float4 per thread
#define CHUNK (BLOCK * SEG)       // 8192 elements per block
#define NF4   (CHUNK / 4)        // 2048 float4 slots in LDS
#define HALO  4096                // windowed-carry history length
#define HSEG  (HALO / BLOCK)      // 16 halo elements per thread
#define HVPT  (HSEG / 4)          // 4 float4 per thread for halo
#define DECAY_THR 1e-8f           // fast path iff (1-a)^HALO < this

typedef float f32x4 __attribute__((ext_vector_type(4)));

__device__ __forceinline__ void nt_store4(float* p, float x, float y, float z, float w) {
    f32x4 v = {x, y, z, w};
    __builtin_nontemporal_store(v, (f32x4*)p);
}

// Bank swizzle on float4 index (involution): spreads both access modes
// (lane-contiguous j=t+256k and thread-segment j=t*8+v) uniformly over the
// 8 bank groups (group = pj%8).
__device__ __forceinline__ int sw(int j) { return j ^ ((j >> 3) & 7); }

// x^(2^k) via repeated squaring
__device__ __forceinline__ float pow2k(float x, int k) {
    float p = x;
#pragma unroll
    for (int i = 0; i < k; ++i) p *= p;
    return p;
}

// Inclusive affine scan across the 64 lanes of a wave (shuffle-based).
__device__ __forceinline__ void wave_scan_affine(float& a, float& b) {
    const int lane = threadIdx.x & 63;
#pragma unroll
    for (int off = 1; off < 64; off <<= 1) {
        float pa = __shfl_up(a, off);
        float pb = __shfl_up(b, off);
        if (lane >= off) {
            b = fmaf(a, pb, b);   // later.a * earlier.b + later.b
            a = pa * a;
        }
    }
}

// Block-wide EXCLUSIVE affine scan (identity for t=0). wa/wb: 4-float LDS
// scratch; caller barriers before reuse. Internal barrier between write/read.
__device__ __forceinline__ void block_exscan_affine(
    float a, float b, float* wa, float* wb, int t, float& ea, float& eb)
{
    float ia = a, ib = b;
    wave_scan_affine(ia, ib);                 // inclusive within wave
    const int w = t >> 6, lane = t & 63;
    if (lane == 63) { wa[w] = ia; wb[w] = ib; }
    float xa = __shfl_up(ia, 1);
    float xb = __shfl_up(ib, 1);
    if (lane == 0) { xa = 1.0f; xb = 0.0f; }
    __syncthreads();
    float pa = 1.0f, pb = 0.0f;               // compose waves 0..w-1 in order
#pragma unroll
    for (int i = 0; i < 3; ++i) {
        if (i < w) {
            float ca = wa[i], cb = wb[i];
            pb = fmaf(ca, pb, cb);
            pa *= ca;
        }
    }
    eb = fmaf(xa, pb, xb);                    // combine(wavePrefix, laneExclusive)
    ea = pa * xa;
}

// Pass 1: per-block affine aggregate. Early-exits when the windowed-carry
// fast path applies (aggregates would never be read).
__global__ __launch_bounds__(BLOCK) void k_block_agg(
    const float* __restrict__ y, const float* __restrict__ alpha_p,
    float* __restrict__ aggA, float* __restrict__ aggB, long n)
{
    const float alpha = alpha_p[0];
    const float oma = 1.0f - alpha;
    if (pow2k(oma, 12) < DECAY_THR) return;   // fast path: skip pass 1 entirely

    const int t = threadIdx.x;
    const long base = (long)blockIdx.x * CHUNK + (long)t * SEG;

    float a = 1.0f, s = 0.0f;
    if (base + SEG <= n) {
        const float4* p = (const float4*)(y + base);
#pragma unroll
        for (int v = 0; v < VPT; ++v) {
            float4 q = p[v];
            s = fmaf(oma, s, alpha * q.x);
            s = fmaf(oma, s, alpha * q.y);
            s = fmaf(oma, s, alpha * q.z);
            s = fmaf(oma, s, alpha * q.w);
        }
        a = pow2k(oma, 5);                    // oma^SEG
    } else {
        for (int k = 0; k < SEG; ++k) {
            long idx = base + k;
            if (idx < n) { s = fmaf(oma, s, alpha * y[idx]); a *= oma; }
        }
    }

    __shared__ float wa[4], wb[4];
    wave_scan_affine(a, s);
    if ((t & 63) == 63) { wa[t >> 6] = a; wb[t >> 6] = s; }
    __syncthreads();
    if (t == 0) {
        float ta = 1.0f, tb = 0.0f;
#pragma unroll
        for (int i = 0; i < 4; ++i) {
            float ca = wa[i], cb = wb[i];
            tb = fmaf(ca, tb, cb);
            ta *= ca;
        }
        aggA[blockIdx.x] = ta;
        aggB[blockIdx.x] = tb;
    }
}

// Pass 2: carry from halo (fast) or aggregate scan (slow); tile marshalled
// through swizzled LDS; cooperative NT stores.
__global__ __launch_bounds__(BLOCK, 4) void k_emit(
    const float* __restrict__ y, const float* __restrict__ alpha_p,
    const float* __restrict__ aggA, const float* __restrict__ aggB,
    float* __restrict__ out, long n, int G)
{
    __shared__ float4 buf[NF4];          // 32 KB tile stage (in, then out)
    __shared__ float wa[4], wb[4];
    __shared__ float s_carry;

    const int t = threadIdx.x;
    // XCD-aware swizzle: consecutive tiles on one XCD. Bijective iff G%8==0.
    int tile = blockIdx.x;
    if ((G & 7) == 0) tile = (tile & 7) * (G >> 3) + (tile >> 3);

    const float alpha = alpha_p[0];
    const float oma   = 1.0f - alpha;
    const bool  fast  = (pow2k(oma, 12) < DECAY_THR);
    const long tbase = (long)tile * CHUNK;
    const long base  = tbase + (long)t * SEG;
    const bool fullTile = (tbase + CHUNK <= n);
    const float y0 = y[0];

    // ---- issue halo loads first (independent, long-latency) ----
    const bool do_halo = fast && (tile > 0);  // tile>0 => tbase >= CHUNK >= HALO
    float4 hq[HVPT];
    if (do_halo) {
        const float4* hp = (const float4*)(y + (tbase - HALO)) + t * HVPT;
#pragma unroll
        for (int v = 0; v < HVPT; ++v) hq[v] = hp[v];
    }

    // ---- cooperative tile load -> swizzled LDS (lane-contiguous global) ----
    if (fullTile) {
        const float4* p4 = (const float4*)(y + tbase);
        float4 tmp[8];
#pragma unroll
        for (int k = 0; k < 8; ++k) tmp[k] = p4[t + (k << 8)];
#pragma unroll
        for (int k = 0; k < 8; ++k) buf[sw(t + (k << 8))] = tmp[k];
    }

    // ---- fast-path carry: halo reduce + wave scan + wave-total fold ----
    float carry = y0;                          // exact for tile 0
    if (do_halo) {
        float hs = 0.0f;
#pragma unroll
        for (int v = 0; v < HVPT; ++v) {
            float4 q = hq[v];
            hs = fmaf(oma, hs, alpha * q.x);
            hs = fmaf(oma, hs, alpha * q.y);
            hs = fmaf(oma, hs, alpha * q.z);
            hs = fmaf(oma, hs, alpha * q.w);
        }
        float ha = pow2k(oma, 4);              // oma^HSEG
        wave_scan_affine(ha, hs);
        if ((t & 63) == 63) { wa[t >> 6] = ha; wb[t >> 6] = hs; }
        __syncthreads();
        float cb_ = 0.0f;                      // fold 4 wave totals; a-term ~0 dropped
#pragma unroll
        for (int i = 0; i < 4; ++i) cb_ = fmaf(wa[i], cb_, wb[i]);
        carry = cb_;                           // dropped term <= 1e-8 * |level|
    }

    __syncthreads();   // buf (tile) visible to all; wa/wb free for exscan

    // ---- per-thread segment reduce from LDS ----
    float a_seg, b_seg;
    if (fullTile) {
        float s = 0.0f;
#pragma unroll
        for (int v = 0; v < VPT; ++v) {
            float4 q = buf[sw(t * VPT + v)];
            s = fmaf(oma, s, alpha * q.x);
            s = fmaf(oma, s, alpha * q.y);
            s = fmaf(oma, s, alpha * q.z);
            s = fmaf(oma, s, alpha * q.w);
        }
        b_seg = s;
        a_seg = pow2k(oma, 5);                 // oma^SEG
    } else {
        float a = 1.0f, s = 0.0f;
        for (int k = 0; k < SEG; ++k) {
            long idx = base + k;
            if (idx < n) { s = fmaf(oma, s, alpha * y[idx]); a *= oma; }
        }
        a_seg = a; b_seg = s;
    }

    // ---- tile exclusive scan ----
    float ea_th, eb_th;
    block_exscan_affine(a_seg, b_seg, wa, wb, t, ea_th, eb_th);

    if (!fast) {
        // ---- slow path: redundant scan of G aggregates -> this tile's carry ----
        const int items = (G + BLOCK - 1) / BLOCK;
        float ta = 1.0f, tb = 0.0f;
        for (int j = 0; j < items; ++j) {
            int g = t * items + j;
            if (g < G) {
                float ca = aggA[g], cb = aggB[g];
                tb = fmaf(ca, tb, cb);
                ta *= ca;
            }
        }
        __syncthreads();                       // wa/wb reads (tile scan) done
        float pa, pb;
        block_exscan_affine(ta, tb, wa, wb, t, pa, pb);
        const int q = tile / items;            // owning thread for this tile's prefix
        if (t == q) {
            float ea = pa, eb = pb;            // aggregates [0, q*items)
            const int r = tile - q * items;    // remaining [q*items, tile)
            for (int j = 0; j < r; ++j) {
                int g = q * items + j;
                float ca = aggA[g], cb = aggB[g];
                eb = fmaf(ca, eb, cb);
                ea *= ca;
            }
            s_carry = fmaf(ea, y0, eb);        // level just before this tile
        }
        __syncthreads();
        carry = s_carry;
    }

    float lvl = fmaf(ea_th, carry, eb_th);     // level just before this segment

    // ---- replay from LDS, write results back in place (own slots only) ----
    if (fullTile) {
#pragma unroll
        for (int v = 0; v < VPT; ++v) {
            const int pj = sw(t * VPT + v);
            float4 q = buf[pj], r;
            lvl = fmaf(oma, lvl, alpha * q.x); r.x = lvl;
            lvl = fmaf(oma, lvl, alpha * q.y); r.y = lvl;
            lvl = fmaf(oma, lvl, alpha * q.z); r.z = lvl;
            lvl = fmaf(oma, lvl, alpha * q.w); r.w = lvl;
            buf[pj] = r;
        }
        __syncthreads();   // all replay writes visible
        // ---- cooperative lane-contiguous NT store (full 64B lines) ----
        const bool lastGuard = (tbase + CHUNK > n - 1);
#pragma unroll
        for (int k = 0; k < 8; ++k) {
            const int j = t + (k << 8);
            float4 r = buf[sw(j)];
            const long gi = tbase + 4L * j;
            if (!lastGuard) {
                nt_store4(out + gi, r.x, r.y, r.z, r.w);
            } else {
                if (gi + 4 <= n - 1) {
                    nt_store4(out + gi, r.x, r.y, r.z, r.w);
                } else {
                    if (gi + 0 < n - 1) out[gi + 0] = r.x;
                    if (gi + 1 < n - 1) out[gi + 1] = r.y;
                    if (gi + 2 < n - 1) out[gi + 2] = r.z;
                    if (gi + 3 < n - 1) out[gi + 3] = r.w;
                }
            }
        }
    } else {
        for (int k = 0; k < SEG; ++k) {
            long idx = base + k;
            if (idx < n) {
                lvl = fmaf(oma, lvl, alpha * y[idx]);
                if (idx < n - 1) out[idx] = lvl;
            }
        }
    }
}

extern "C" void kernel_launch(void* const* d_in, const int* in_sizes, int n_in,
                              void* d_out, int out_size, void* d_ws, size_t ws_size,
                              hipStream_t stream) {
    const float* y     = (const float*)d_in[0];
    const float* alpha = (const float*)d_in[1];
    float* out = (float*)d_out;
    const long n = (long)in_sizes[0];
    const int  G = (int)((n + CHUNK - 1) / CHUNK);   // 2048 for n = 2^24

    float* aggA = (float*)d_ws;        // G floats (written only on slow path)
    float* aggB = aggA + G;            // G floats

    k_block_agg<<<G, BLOCK, 0, stream>>>(y, alpha, aggA, aggB, n);
    k_emit<<<G, BLOCK, 0, stream>>>(y, alpha, aggA, aggB, out, n, G);
}